// Round 7
// baseline (49.952 us; speedup 1.0000x reference)
//
#include <hip/hip_runtime.h>

#define DIM 1024
#define RPT 4        // rows per tile (amortizes weight loads over 4 rows)
#define WAVES 4      // waves per block
#define TILES_PER_WAVE 2
#define PACKED_BYTES (6 * 4 * 64 * 8 * 4)   // stages 2..7, 4 q, 64 lanes, 8 floats

typedef float f32x4 __attribute__((ext_vector_type(4)));  // native vec for NT builtins

// Butterfly mixer: 10 stages, stage i mixes (j, j+2^i) with Ws[i][p], p = j with bit i removed.
// Element j = q*256 + lane*4 + c  (q,c in [0,4), lane in [0,64)) lives in d[*][q*4+c].
// -> bits {0,1} = c, bits {2..7} = lane, bits {8,9} = q.
// Stages 0,1,8,9 are thread-local; stages 2..7 are __shfl_xor with mask 2^(i-2).
// NOTE: never use the 2nd __launch_bounds__ arg here — measured VGPR cap ~256/minwaves
// (r2: w=5 -> 48 VGPR, r4: w=4 -> 64 VGPR) forces scratch spills. Compiler-chosen
// allocation has zero spill (r1: 128, r6: 100).
// Structure (r7): each wave owns 2 consecutive 4-row tiles. All 32 NT loads issued
// up front; compute of tile A runs while tile B's loads are in flight (counted
// vmcnt keeps them outstanding). 2048 waves = 2/SIMD -> all resident at any VGPR.

__global__ void pack_weights(const float* __restrict__ Ws, float* __restrict__ pw) {
    int t = blockIdx.x * blockDim.x + threadIdx.x; // 0..1535
    if (t >= 6 * 4 * 64) return;
    int lane = t & 63;
    int q = (t >> 6) & 3;
    int i = (t >> 8) + 2;          // 2..7
    int m = 1 << (i - 2);
    int a = (lane >> (i - 2)) & 1;
    int P0 = (((q * 64 + lane) >> (i - 1)) << i) | ((lane & (m - 1)) << 2);
    const float4* Wm = (const float4*)Ws;
    float4 wa, wb;
    float* pa = (float*)&wa;
    float* pb = (float*)&wb;
    #pragma unroll
    for (int e = 0; e < 4; ++e) {
        float4 M = Wm[i * 512 + P0 + e];
        pa[e] = a ? M.w : M.x;     // coeff multiplying my own value
        pb[e] = a ? M.y : M.z;     // coeff multiplying partner's value
    }
    float4* o = (float4*)pw + (size_t)t * 2;
    o[0] = wa;
    o[1] = wb;
}

__device__ __forceinline__ void load_tile(const float* __restrict__ x, int tile,
                                          int lane, float (&d)[RPT][16]) {
    const f32x4* src = (const f32x4*)(x + (size_t)tile * RPT * DIM);
    #pragma unroll
    for (int r = 0; r < RPT; ++r) {
        #pragma unroll
        for (int q = 0; q < 4; ++q) {
            f32x4 v = __builtin_nontemporal_load(&src[r * 256 + q * 64 + lane]);
            d[r][q*4+0] = v.x; d[r][q*4+1] = v.y;
            d[r][q*4+2] = v.z; d[r][q*4+3] = v.w;
        }
    }
}

__device__ __forceinline__ void store_tile(float* __restrict__ out, int tile,
                                           int lane, float (&d)[RPT][16]) {
    f32x4* dst = (f32x4*)(out + (size_t)tile * RPT * DIM);
    #pragma unroll
    for (int r = 0; r < RPT; ++r) {
        #pragma unroll
        for (int q = 0; q < 4; ++q) {
            f32x4 v;
            v.x = d[r][q*4+0]; v.y = d[r][q*4+1];
            v.z = d[r][q*4+2]; v.w = d[r][q*4+3];
            __builtin_nontemporal_store(v, &dst[r * 256 + q * 64 + lane]);
        }
    }
}

template <bool PACKED>
__device__ __forceinline__ void compute_tile(float (&d)[RPT][16],
                                             const float4* __restrict__ Wm,
                                             const float* __restrict__ pw,
                                             int lane) {
    // ---- stage 0: pairs (c,c+1); p = q*128 + lane*2 + (c>>1) ----
    #pragma unroll
    for (int q = 0; q < 4; ++q) {
        int base = 0*512 + q*128 + lane*2;
        float4 m0 = Wm[base], m1 = Wm[base+1];
        #pragma unroll
        for (int r = 0; r < RPT; ++r) {
            int e = q*4;
            float u = d[r][e+0], v = d[r][e+1];
            d[r][e+0] = u*m0.x + v*m0.z;
            d[r][e+1] = u*m0.y + v*m0.w;
            u = d[r][e+2]; v = d[r][e+3];
            d[r][e+2] = u*m1.x + v*m1.z;
            d[r][e+3] = u*m1.y + v*m1.w;
        }
    }

    // ---- stage 1: pairs (c,c+2); p = q*128 + lane*2 + (c&1) ----
    #pragma unroll
    for (int q = 0; q < 4; ++q) {
        int base = 1*512 + q*128 + lane*2;
        float4 m0 = Wm[base], m1 = Wm[base+1];
        #pragma unroll
        for (int r = 0; r < RPT; ++r) {
            int e = q*4;
            float u = d[r][e+0], v = d[r][e+2];
            d[r][e+0] = u*m0.x + v*m0.z;
            d[r][e+2] = u*m0.y + v*m0.w;
            u = d[r][e+1]; v = d[r][e+3];
            d[r][e+1] = u*m1.x + v*m1.z;
            d[r][e+3] = u*m1.y + v*m1.w;
        }
    }

    // ---- stages 2..7: cross-lane, mask m = 2^(i-2) ----
    #pragma unroll
    for (int i = 2; i < 8; ++i) {
        const int m = 1 << (i - 2);
        #pragma unroll
        for (int q = 0; q < 4; ++q) {
            float wA0, wA1, wA2, wA3, wB0, wB1, wB2, wB3;
            if (PACKED) {
                const float4* wp = (const float4*)pw
                    + ((size_t)(((i - 2) * 4 + q) * 64 + lane)) * 2;
                float4 wa = wp[0], wb = wp[1];
                wA0 = wa.x; wA1 = wa.y; wA2 = wa.z; wA3 = wa.w;
                wB0 = wb.x; wB1 = wb.y; wB2 = wb.z; wB3 = wb.w;
            } else {
                const int a = (lane >> (i - 2)) & 1;
                int P0 = (((q*64 + lane) >> (i-1)) << i) | ((lane & (m-1)) << 2);
                int base = i*512 + P0;
                float4 M0 = Wm[base+0], M1 = Wm[base+1], M2 = Wm[base+2], M3 = Wm[base+3];
                wA0 = a ? M0.w : M0.x; wB0 = a ? M0.y : M0.z;
                wA1 = a ? M1.w : M1.x; wB1 = a ? M1.y : M1.z;
                wA2 = a ? M2.w : M2.x; wB2 = a ? M2.y : M2.z;
                wA3 = a ? M3.w : M3.x; wB3 = a ? M3.y : M3.z;
            }
            #pragma unroll
            for (int r = 0; r < RPT; ++r) {
                int e = q*4;
                float o0 = __shfl_xor(d[r][e+0], m);
                float o1 = __shfl_xor(d[r][e+1], m);
                float o2 = __shfl_xor(d[r][e+2], m);
                float o3 = __shfl_xor(d[r][e+3], m);
                d[r][e+0] = d[r][e+0]*wA0 + o0*wB0;
                d[r][e+1] = d[r][e+1]*wA1 + o1*wB1;
                d[r][e+2] = d[r][e+2]*wA2 + o2*wB2;
                d[r][e+3] = d[r][e+3]*wA3 + o3*wB3;
            }
        }
    }

    // ---- stage 8: pairs (q, q+1) for q in {0,2}; p = (q>>1)*256 + lane*4 + c ----
    #pragma unroll
    for (int qp = 0; qp < 2; ++qp) {
        int base = 8*512 + qp*256 + lane*4;
        float4 M0 = Wm[base+0], M1 = Wm[base+1], M2 = Wm[base+2], M3 = Wm[base+3];
        #pragma unroll
        for (int r = 0; r < RPT; ++r) {
            int eu = (2*qp)*4, ev = (2*qp+1)*4;
            float u, v;
            u = d[r][eu+0]; v = d[r][ev+0]; d[r][eu+0] = u*M0.x + v*M0.z; d[r][ev+0] = u*M0.y + v*M0.w;
            u = d[r][eu+1]; v = d[r][ev+1]; d[r][eu+1] = u*M1.x + v*M1.z; d[r][ev+1] = u*M1.y + v*M1.w;
            u = d[r][eu+2]; v = d[r][ev+2]; d[r][eu+2] = u*M2.x + v*M2.z; d[r][ev+2] = u*M2.y + v*M2.w;
            u = d[r][eu+3]; v = d[r][ev+3]; d[r][eu+3] = u*M3.x + v*M3.z; d[r][ev+3] = u*M3.y + v*M3.w;
        }
    }

    // ---- stage 9: pairs (q, q+2) for q in {0,1}; p = (q&1)*256 + lane*4 + c ----
    #pragma unroll
    for (int qp = 0; qp < 2; ++qp) {
        int base = 9*512 + qp*256 + lane*4;
        float4 M0 = Wm[base+0], M1 = Wm[base+1], M2 = Wm[base+2], M3 = Wm[base+3];
        #pragma unroll
        for (int r = 0; r < RPT; ++r) {
            int eu = qp*4, ev = (qp+2)*4;
            float u, v;
            u = d[r][eu+0]; v = d[r][ev+0]; d[r][eu+0] = u*M0.x + v*M0.z; d[r][ev+0] = u*M0.y + v*M0.w;
            u = d[r][eu+1]; v = d[r][ev+1]; d[r][eu+1] = u*M1.x + v*M1.z; d[r][ev+1] = u*M1.y + v*M1.w;
            u = d[r][eu+2]; v = d[r][ev+2]; d[r][eu+2] = u*M2.x + v*M2.z; d[r][ev+2] = u*M2.y + v*M2.w;
            u = d[r][eu+3]; v = d[r][ev+3]; d[r][eu+3] = u*M3.x + v*M3.z; d[r][ev+3] = u*M3.y + v*M3.w;
        }
    }
}

template <bool PACKED>
__global__ __launch_bounds__(256) void butterfly_kernel(
    const float* __restrict__ x,
    const float* __restrict__ Ws,
    const float* __restrict__ pw,
    float* __restrict__ out,
    int ntiles)
{
    const int lane = threadIdx.x & 63;
    const int wave = threadIdx.x >> 6;
    const int g = blockIdx.x * WAVES + wave;     // global wave id
    const int tA = g * TILES_PER_WAVE;
    const int tB = tA + 1;

    const float4* __restrict__ Wm = (const float4*)Ws;

    float dA[RPT][16], dB[RPT][16];
    const bool hasA = tA < ntiles;
    const bool hasB = tB < ntiles;

    // Issue ALL loads up front: B's loads stay in flight under A's compute.
    if (hasA) load_tile(x, tA, lane, dA);
    if (hasB) load_tile(x, tB, lane, dB);

    if (hasA) {
        compute_tile<PACKED>(dA, Wm, pw, lane);
        store_tile(out, tA, lane, dA);
    }
    if (hasB) {
        compute_tile<PACKED>(dB, Wm, pw, lane);
        store_tile(out, tB, lane, dB);
    }
}

extern "C" void kernel_launch(void* const* d_in, const int* in_sizes, int n_in,
                              void* d_out, int out_size, void* d_ws, size_t ws_size,
                              hipStream_t stream) {
    const float* x  = (const float*)d_in[0];
    const float* Ws = (const float*)d_in[1];
    float* out = (float*)d_out;

    int rows = in_sizes[0] / DIM;
    int ntiles = rows / RPT;                         // 4096 (rows % RPT == 0 here)
    int tiles_per_block = WAVES * TILES_PER_WAVE;    // 8
    int grid = (ntiles + tiles_per_block - 1) / tiles_per_block;  // 512

    if (ws_size >= (size_t)PACKED_BYTES) {
        float* pw = (float*)d_ws;
        pack_weights<<<6, 256, 0, stream>>>(Ws, pw);
        butterfly_kernel<true><<<grid, 256, 0, stream>>>(x, Ws, pw, out, ntiles);
    } else {
        butterfly_kernel<false><<<grid, 256, 0, stream>>>(x, Ws, nullptr, out, ntiles);
    }
}

// Round 8
// 43.504 us; speedup vs baseline: 1.1482x; 1.1482x over previous
//
#include <hip/hip_runtime.h>

#define DIM 1024
#define RPW 2        // rows per wave
#define WAVES 4      // waves per block
#define ROWS_PER_BLOCK (RPW * WAVES)
#define NSTEP 24                            // stages 2..7 x 4 q
#define PACKED_BYTES (NSTEP * 64 * 8 * 4)   // 48 KB: wa region (24KB) + wb region (24KB)
#define WLDS_FLOATS (NSTEP * 64 * 8)        // 12288 floats

typedef float f32x4 __attribute__((ext_vector_type(4)));

// Butterfly mixer: 10 stages, stage i mixes (j, j+2^i) with Ws[i][p], p = j with bit i removed.
// Element j = q*256 + lane*4 + c  (q,c in [0,4), lane in [0,64)) lives in d[r][q*4+c].
// Stages 0,1,8,9 thread-local; stages 2..7 are __shfl_xor with mask 2^(i-2).
// r8: packed stage-2..7 weights (48KB, shared by ALL waves) staged in LDS per block
// via global_load_lds -> weight fetches leave the L2 latency path. Split wa/wb
// regions so ds_read_b128 has 16B lane stride (conflict-free canonical pattern).
// NOTE: never use the 2nd __launch_bounds__ arg (spill cliff: r2/r4).

// Pack: wa[step][lane] = 4 diag coeffs, wb[step][lane] = 4 partner coeffs.
// step = (i-2)*4 + q. Layouts are float4 at (step*64+lane)*4 floats, wb offset +6144.
__global__ void pack_weights(const float* __restrict__ Ws, float* __restrict__ pw) {
    int t = blockIdx.x * blockDim.x + threadIdx.x; // 0..1535
    if (t >= NSTEP * 64) return;
    int lane = t & 63;
    int step = t >> 6;            // 0..23
    int q = step & 3;
    int i = (step >> 2) + 2;      // 2..7
    int m = 1 << (i - 2);
    int a = (lane >> (i - 2)) & 1;
    int P0 = (((q * 64 + lane) >> (i - 1)) << i) | ((lane & (m - 1)) << 2);
    const float4* Wm = (const float4*)Ws;
    float4 wa, wb;
    float* pa = (float*)&wa;
    float* pb = (float*)&wb;
    #pragma unroll
    for (int e = 0; e < 4; ++e) {
        float4 M = Wm[i * 512 + P0 + e];
        pa[e] = a ? M.w : M.x;
        pb[e] = a ? M.y : M.z;
    }
    ((float4*)pw)[t] = wa;                       // wa region: [0, 6144) floats
    ((float4*)pw)[(WLDS_FLOATS / 8) + t] = wb;   // wb region: [6144, 12288) floats
}

template <bool PACKED>
__global__ __launch_bounds__(256) void butterfly_kernel(
    const float* __restrict__ x,
    const float* __restrict__ Ws,
    const float* __restrict__ pw,
    float* __restrict__ out,
    int rows)
{
    const int lane = threadIdx.x & 63;
    const int wave = threadIdx.x >> 6;
    const int row0 = (blockIdx.x * WAVES + wave) * RPW;

    const float4* __restrict__ Wm = (const float4*)Ws;

    __shared__ float wlds[WLDS_FLOATS];   // 48 KB -> 3 blocks/CU

    float d[RPW][16];

    // ---- issue x loads first (HBM latency overlaps the LDS staging) ----
    #pragma unroll
    for (int r = 0; r < RPW; ++r) {
        int row = row0 + r;
        if (row < rows) {
            const f32x4* src = (const f32x4*)(x + (size_t)row * DIM);
            #pragma unroll
            for (int q = 0; q < 4; ++q) {
                f32x4 v = __builtin_nontemporal_load(&src[q * 64 + lane]);
                d[r][q*4+0] = v.x; d[r][q*4+1] = v.y;
                d[r][q*4+2] = v.z; d[r][q*4+3] = v.w;
            }
        } else {
            #pragma unroll
            for (int e = 0; e < 16; ++e) d[r][e] = 0.f;
        }
    }

    // ---- stage packed weights into LDS: 48 chunks of 1KB, 12 per wave ----
    if (PACKED) {
        #pragma unroll
        for (int k = 0; k < 12; ++k) {
            int chunk = wave * 12 + k;                 // 0..47
            const float* g = pw + chunk * 256 + lane * 4;
            float* l = &wlds[chunk * 256 + lane * 4];
            __builtin_amdgcn_global_load_lds(g, l, 16, 0, 0);
        }
        __syncthreads();
    }

    // ---- stage 0: pairs (c,c+1); p = q*128 + lane*2 + (c>>1) ----
    #pragma unroll
    for (int q = 0; q < 4; ++q) {
        int base = 0*512 + q*128 + lane*2;
        float4 m0 = Wm[base], m1 = Wm[base+1];
        #pragma unroll
        for (int r = 0; r < RPW; ++r) {
            int e = q*4;
            float u = d[r][e+0], v = d[r][e+1];
            d[r][e+0] = u*m0.x + v*m0.z;
            d[r][e+1] = u*m0.y + v*m0.w;
            u = d[r][e+2]; v = d[r][e+3];
            d[r][e+2] = u*m1.x + v*m1.z;
            d[r][e+3] = u*m1.y + v*m1.w;
        }
    }

    // ---- stage 1: pairs (c,c+2); p = q*128 + lane*2 + (c&1) ----
    #pragma unroll
    for (int q = 0; q < 4; ++q) {
        int base = 1*512 + q*128 + lane*2;
        float4 m0 = Wm[base], m1 = Wm[base+1];
        #pragma unroll
        for (int r = 0; r < RPW; ++r) {
            int e = q*4;
            float u = d[r][e+0], v = d[r][e+2];
            d[r][e+0] = u*m0.x + v*m0.z;
            d[r][e+2] = u*m0.y + v*m0.w;
            u = d[r][e+1]; v = d[r][e+3];
            d[r][e+1] = u*m1.x + v*m1.z;
            d[r][e+3] = u*m1.y + v*m1.w;
        }
    }

    // ---- stages 2..7: cross-lane, mask m = 2^(i-2); weights from LDS ----
    #pragma unroll
    for (int i = 2; i < 8; ++i) {
        const int m = 1 << (i - 2);
        #pragma unroll
        for (int q = 0; q < 4; ++q) {
            const int step = (i - 2) * 4 + q;
            float wA0, wA1, wA2, wA3, wB0, wB1, wB2, wB3;
            if (PACKED) {
                f32x4 wa = *(const f32x4*)&wlds[(step * 64 + lane) * 4];
                f32x4 wb = *(const f32x4*)&wlds[(WLDS_FLOATS / 2) + (step * 64 + lane) * 4];
                wA0 = wa.x; wA1 = wa.y; wA2 = wa.z; wA3 = wa.w;
                wB0 = wb.x; wB1 = wb.y; wB2 = wb.z; wB3 = wb.w;
            } else {
                const int a = (lane >> (i - 2)) & 1;
                int P0 = (((q*64 + lane) >> (i-1)) << i) | ((lane & (m-1)) << 2);
                int base = i*512 + P0;
                float4 M0 = Wm[base+0], M1 = Wm[base+1], M2 = Wm[base+2], M3 = Wm[base+3];
                wA0 = a ? M0.w : M0.x; wB0 = a ? M0.y : M0.z;
                wA1 = a ? M1.w : M1.x; wB1 = a ? M1.y : M1.z;
                wA2 = a ? M2.w : M2.x; wB2 = a ? M2.y : M2.z;
                wA3 = a ? M3.w : M3.x; wB3 = a ? M3.y : M3.z;
            }
            #pragma unroll
            for (int r = 0; r < RPW; ++r) {
                int e = q*4;
                float o0 = __shfl_xor(d[r][e+0], m);
                float o1 = __shfl_xor(d[r][e+1], m);
                float o2 = __shfl_xor(d[r][e+2], m);
                float o3 = __shfl_xor(d[r][e+3], m);
                d[r][e+0] = d[r][e+0]*wA0 + o0*wB0;
                d[r][e+1] = d[r][e+1]*wA1 + o1*wB1;
                d[r][e+2] = d[r][e+2]*wA2 + o2*wB2;
                d[r][e+3] = d[r][e+3]*wA3 + o3*wB3;
            }
        }
    }

    // ---- stage 8: pairs (q, q+1) for q in {0,2}; p = (q>>1)*256 + lane*4 + c ----
    #pragma unroll
    for (int qp = 0; qp < 2; ++qp) {
        int base = 8*512 + qp*256 + lane*4;
        float4 M0 = Wm[base+0], M1 = Wm[base+1], M2 = Wm[base+2], M3 = Wm[base+3];
        #pragma unroll
        for (int r = 0; r < RPW; ++r) {
            int eu = (2*qp)*4, ev = (2*qp+1)*4;
            float u, v;
            u = d[r][eu+0]; v = d[r][ev+0]; d[r][eu+0] = u*M0.x + v*M0.z; d[r][ev+0] = u*M0.y + v*M0.w;
            u = d[r][eu+1]; v = d[r][ev+1]; d[r][eu+1] = u*M1.x + v*M1.z; d[r][ev+1] = u*M1.y + v*M1.w;
            u = d[r][eu+2]; v = d[r][ev+2]; d[r][eu+2] = u*M2.x + v*M2.z; d[r][ev+2] = u*M2.y + v*M2.w;
            u = d[r][eu+3]; v = d[r][ev+3]; d[r][eu+3] = u*M3.x + v*M3.z; d[r][ev+3] = u*M3.y + v*M3.w;
        }
    }

    // ---- stage 9: pairs (q, q+2) for q in {0,1}; p = (q&1)*256 + lane*4 + c ----
    #pragma unroll
    for (int qp = 0; qp < 2; ++qp) {
        int base = 9*512 + qp*256 + lane*4;
        float4 M0 = Wm[base+0], M1 = Wm[base+1], M2 = Wm[base+2], M3 = Wm[base+3];
        #pragma unroll
        for (int r = 0; r < RPW; ++r) {
            int eu = qp*4, ev = (qp+2)*4;
            float u, v;
            u = d[r][eu+0]; v = d[r][ev+0]; d[r][eu+0] = u*M0.x + v*M0.z; d[r][ev+0] = u*M0.y + v*M0.w;
            u = d[r][eu+1]; v = d[r][ev+1]; d[r][eu+1] = u*M1.x + v*M1.z; d[r][ev+1] = u*M1.y + v*M1.w;
            u = d[r][eu+2]; v = d[r][ev+2]; d[r][eu+2] = u*M2.x + v*M2.z; d[r][ev+2] = u*M2.y + v*M2.w;
            u = d[r][eu+3]; v = d[r][ev+3]; d[r][eu+3] = u*M3.x + v*M3.z; d[r][ev+3] = u*M3.y + v*M3.w;
        }
    }

    // ---- store: coalesced float4, nontemporal ----
    #pragma unroll
    for (int r = 0; r < RPW; ++r) {
        int row = row0 + r;
        if (row < rows) {
            f32x4* dst = (f32x4*)(out + (size_t)row * DIM);
            #pragma unroll
            for (int q = 0; q < 4; ++q) {
                f32x4 v;
                v.x = d[r][q*4+0]; v.y = d[r][q*4+1];
                v.z = d[r][q*4+2]; v.w = d[r][q*4+3];
                __builtin_nontemporal_store(v, &dst[q * 64 + lane]);
            }
        }
    }
}

extern "C" void kernel_launch(void* const* d_in, const int* in_sizes, int n_in,
                              void* d_out, int out_size, void* d_ws, size_t ws_size,
                              hipStream_t stream) {
    const float* x  = (const float*)d_in[0];
    const float* Ws = (const float*)d_in[1];
    float* out = (float*)d_out;

    int rows = in_sizes[0] / DIM;
    int grid = (rows + ROWS_PER_BLOCK - 1) / ROWS_PER_BLOCK;

    if (ws_size >= (size_t)PACKED_BYTES) {
        float* pw = (float*)d_ws;
        pack_weights<<<6, 256, 0, stream>>>(Ws, pw);
        butterfly_kernel<true><<<grid, 256, 0, stream>>>(x, Ws, pw, out, rows);
    } else {
        butterfly_kernel<false><<<grid, 256, 0, stream>>>(x, Ws, nullptr, out, rows);
    }
}